// Round 10
// baseline (407.813 us; speedup 1.0000x reference)
//
#include <hip/hip_runtime.h>
#include <hip/hip_bf16.h>

#define NEG_SLOPE 0.2f
#define G_SHIFT 7
#define GSZ 128          // nodes per bucket
#define CHUNK 4096       // edges per coarse block; also per-bucket region capacity

// ---------- coarse scatter: bucket edges, u32-packed, coalesced writes ------
__global__ __launch_bounds__(256) void coarse_scatter(
    const int* __restrict__ src, const int* __restrict__ dst,
    int* __restrict__ gcursor, unsigned* __restrict__ inter, int NB, int E) {
    __shared__ int hist[800];
    __shared__ int lbase[800];
    __shared__ int gbase[800];
    __shared__ unsigned stage[CHUNK];
    __shared__ unsigned short bstage[CHUNK];

    const int tid = threadIdx.x;
    const int e0 = blockIdx.x * CHUNK;
    const int cnt = min(CHUNK, E - e0);

    for (int i = tid; i < NB; i += 256) hist[i] = 0;
    __syncthreads();

    unsigned pk[16];
    int bb[16];
#pragma unroll
    for (int r = 0; r < 16; ++r) {
        int idx = tid + r * 256;
        if (idx < cnt) {
            int s = src[e0 + idx];
            int d = dst[e0 + idx];
            pk[r] = ((unsigned)s << G_SHIFT) | (unsigned)(d & (GSZ - 1));
            bb[r] = d >> G_SHIFT;
            atomicAdd(&hist[bb[r]], 1);
        }
    }
    __syncthreads();
    if (tid < 64) {
        int carry = 0;
        for (int i = 0; i < NB; i += 64) {
            int v = (i + tid < NB) ? hist[i + tid] : 0;
            int xv = v;
            for (int o = 1; o < 64; o <<= 1) {
                int tt = __shfl_up(xv, o, 64);
                if (tid >= o) xv += tt;
            }
            if (i + tid < NB) lbase[i + tid] = carry + xv - v;
            carry += __shfl(xv, 63, 64);
        }
    }
    __syncthreads();
    for (int i = tid; i < NB; i += 256) {
        int hh = hist[i];
        gbase[i] = (hh > 0) ? (i * CHUNK + atomicAdd(&gcursor[i], hh)) : 0;
    }
    __syncthreads();
    for (int i = tid; i < NB; i += 256) hist[i] = 0;
    __syncthreads();
#pragma unroll
    for (int r = 0; r < 16; ++r) {
        int idx = tid + r * 256;
        if (idx < cnt) {
            int b = bb[r];
            int rk = atomicAdd(&hist[b], 1);
            int pos = lbase[b] + rk;
            stage[pos] = pk[r];
            bstage[pos] = (unsigned short)b;
        }
    }
    __syncthreads();
#pragma unroll
    for (int r = 0; r < 16; ++r) {
        int idx = tid + r * 256;
        if (idx < cnt) {
            int b = (int)bstage[idx];
            inter[gbase[b] + (idx - lbase[b])] = stage[idx];
        }
    }
}

// ---------- fused: gemm1 (+el/er, bf16 out) blocks, then fine-scatter blocks -
union K2Smem {
    struct { float xs[32][68]; float ws[32][128]; } g;                  // 25088 B
    struct { int h[GSZ]; int lb[GSZ]; int stage[CHUNK]; int redsum[256]; } f; // 18432 B
};

__global__ __launch_bounds__(256) void gemm1_fine_fused(
    // gemm1 args
    const float* __restrict__ x, const float* __restrict__ W,
    const float* __restrict__ al, const float* __restrict__ ar,
    __hip_bfloat16* __restrict__ outb, float* __restrict__ el,
    float* __restrict__ er, int N, int NG,
    // fine args
    const unsigned* __restrict__ inter, const int* __restrict__ gcursor,
    int* __restrict__ deg, int* __restrict__ rowptr, int* __restrict__ esrc,
    int NB) {
    __shared__ K2Smem sm;
    const int tid = threadIdx.x;

    if ((int)blockIdx.x < NG) {
        // ================= gemm1 + fused el/er =================
        const int K = 128, C = 128, BK = 32;
        const int trow = tid >> 4;
        const int tcol = tid & 15;
        const int m0 = blockIdx.x * 64;

        float acc[4][8];
#pragma unroll
        for (int i = 0; i < 4; ++i)
#pragma unroll
            for (int j = 0; j < 8; ++j) acc[i][j] = 0.f;

        for (int k0 = 0; k0 < K; k0 += BK) {
            {
                const float4* W4 = (const float4*)(W + k0 * C);
#pragma unroll
                for (int r = 0; r < 4; ++r) {
                    int q = tid + 256 * r;
                    int k = q >> 5;
                    int c4 = q & 31;
                    float4 v = W4[k * 32 + c4];
                    *((float4*)&sm.g.ws[k][c4 * 4]) = v;
                }
            }
            {
#pragma unroll
                for (int r = 0; r < 2; ++r) {
                    int q = tid + 256 * r;
                    int m = q >> 3;
                    int k4 = q & 7;
                    int gm = m0 + m;
                    if (gm >= N) gm = N - 1;
                    float4 v = *((const float4*)(x + (size_t)gm * K + k0 + k4 * 4));
                    sm.g.xs[k4 * 4 + 0][m] = v.x;
                    sm.g.xs[k4 * 4 + 1][m] = v.y;
                    sm.g.xs[k4 * 4 + 2][m] = v.z;
                    sm.g.xs[k4 * 4 + 3][m] = v.w;
                }
            }
            __syncthreads();

#pragma unroll
            for (int k = 0; k < BK; ++k) {
                float4 a = *((const float4*)&sm.g.xs[k][trow * 4]);
                float4 b0 = *((const float4*)&sm.g.ws[k][tcol * 8]);
                float4 b1 = *((const float4*)&sm.g.ws[k][tcol * 8 + 4]);
                float av[4] = {a.x, a.y, a.z, a.w};
                float bv[8] = {b0.x, b0.y, b0.z, b0.w, b1.x, b1.y, b1.z, b1.w};
#pragma unroll
                for (int i = 0; i < 4; ++i)
#pragma unroll
                    for (int j = 0; j < 8; ++j) acc[i][j] += av[i] * bv[j];
            }
            __syncthreads();
        }

        const int h = tcol >> 2;
        const int d0 = (tcol & 3) * 8;
        float alv[8], arv[8];
#pragma unroll
        for (int j = 0; j < 8; ++j) {
            alv[j] = al[h * 32 + d0 + j];
            arv[j] = ar[h * 32 + d0 + j];
        }
#pragma unroll
        for (int i = 0; i < 4; ++i) {
            int gm = m0 + trow * 4 + i;
            if (gm < N) {
                union { __hip_bfloat16 hh[8]; uint4 u; } pk;
#pragma unroll
                for (int j = 0; j < 8; ++j) pk.hh[j] = __float2bfloat16(acc[i][j]);
                *((uint4*)(outb + (size_t)gm * C + tcol * 8)) = pk.u;
            }
            float pl = 0.f, pr = 0.f;
#pragma unroll
            for (int j = 0; j < 8; ++j) {
                pl += acc[i][j] * alv[j];
                pr += acc[i][j] * arv[j];
            }
            pl += __shfl_xor(pl, 1); pl += __shfl_xor(pl, 2);
            pr += __shfl_xor(pr, 1); pr += __shfl_xor(pr, 2);
            if ((tcol & 3) == 0 && gm < N) {
                el[gm * 4 + h] = pl;
                er[gm * 4 + h] = pr;
            }
        }
    } else {
        // ================= fine scatter =================
        const int b = (int)blockIdx.x - NG;
        const int cnt = gcursor[b];
        const unsigned* ep = inter + (size_t)b * CHUNK;

        // bucket base = sum gcursor[0..b)
        {
            int s = 0;
            for (int i = tid; i < b; i += 256) s += gcursor[i];
            sm.f.redsum[tid] = s;
            __syncthreads();
            for (int o = 128; o > 0; o >>= 1) {
                if (tid < o) sm.f.redsum[tid] += sm.f.redsum[tid + o];
                __syncthreads();
            }
        }
        const int base = sm.f.redsum[0];

        if (tid < GSZ) sm.f.h[tid] = 0;
        __syncthreads();

        int ss[16];
        unsigned char ln[16];
        int nr = 0;
        for (int idx = tid; idx < cnt; idx += 256) {
            unsigned ed = ep[idx];
            ss[nr] = (int)(ed >> G_SHIFT);
            int l = (int)(ed & (GSZ - 1));
            ln[nr++] = (unsigned char)l;
            atomicAdd(&sm.f.h[l], 1);
        }
        __syncthreads();
        if (tid < 64) {
            int carry = 0;
            for (int i = 0; i < GSZ; i += 64) {
                int v = sm.f.h[i + tid];
                int xv = v;
                for (int o = 1; o < 64; o <<= 1) {
                    int tt = __shfl_up(xv, o, 64);
                    if (tid >= o) xv += tt;
                }
                sm.f.lb[i + tid] = carry + xv - v;
                carry += __shfl(xv, 63, 64);
            }
        }
        __syncthreads();
        if (tid < GSZ) {
            int node = b * GSZ + tid;
            if (node < N) {
                deg[node] = sm.f.h[tid];
                rowptr[node] = base + sm.f.lb[tid];
            }
            sm.f.h[tid] = 0;
        }
        __syncthreads();
        for (int r = 0; r < nr; ++r) {
            int l = ln[r];
            int rk = atomicAdd(&sm.f.h[l], 1);
            sm.f.stage[sm.f.lb[l] + rk] = ss[r];
        }
        __syncthreads();
        for (int idx = tid; idx < cnt; idx += 256) esrc[base + idx] = sm.f.stage[idx];
    }
}

__device__ __forceinline__ float bf2f(unsigned short v) {
    return __uint_as_float((unsigned)v << 16);
}

// ---------- layer-1 pull (32 lanes/node, 4x unroll) + fused gemm2/el2/er2 ---
__global__ __launch_bounds__(256) void pull1_kernel(
    const int* __restrict__ rowptr, const int* __restrict__ deg,
    const int* __restrict__ esrc, const float* __restrict__ el,
    const float* __restrict__ er, const __hip_bfloat16* __restrict__ featb,
    const float* __restrict__ b,
    const float* __restrict__ W2, const float* __restrict__ al2,
    const float* __restrict__ ar2, float* __restrict__ feat2,
    float* __restrict__ el2, float* __restrict__ er2, int N) {
    int tid = blockIdx.x * 256 + threadIdx.x;
    int node = tid >> 5;
    int lane = threadIdx.x & 31;
    int h = lane >> 3;
    int d4 = lane & 7;
    if (node >= N) return;

    int start = rowptr[node];
    int cnt = deg[node];
    float er_nh = er[node * 4 + h];
    const int* ep = esrc + start;
    const unsigned short* fb = (const unsigned short*)featb + h * 32 + d4 * 4;

    float4 acc = make_float4(0.f, 0.f, 0.f, 0.f);
    float sumex = 0.f;

    int i = 0;
    for (; i + 4 <= cnt; i += 4) {
        int s0 = ep[i], s1 = ep[i + 1], s2 = ep[i + 2], s3 = ep[i + 3];
        float e0 = el[s0 * 4 + h], e1 = el[s1 * 4 + h];
        float e2 = el[s2 * 4 + h], e3 = el[s3 * 4 + h];
        ushort4 u0 = *((const ushort4*)(fb + (size_t)s0 * 128));
        ushort4 u1 = *((const ushort4*)(fb + (size_t)s1 * 128));
        ushort4 u2 = *((const ushort4*)(fb + (size_t)s2 * 128));
        ushort4 u3 = *((const ushort4*)(fb + (size_t)s3 * 128));
        float v0 = e0 + er_nh; v0 = v0 > 0.f ? v0 : NEG_SLOPE * v0;
        float v1 = e1 + er_nh; v1 = v1 > 0.f ? v1 : NEG_SLOPE * v1;
        float v2 = e2 + er_nh; v2 = v2 > 0.f ? v2 : NEG_SLOPE * v2;
        float v3 = e3 + er_nh; v3 = v3 > 0.f ? v3 : NEG_SLOPE * v3;
        float x0 = __expf(v0), x1 = __expf(v1), x2 = __expf(v2), x3 = __expf(v3);
        acc.x += x0 * bf2f(u0.x); acc.y += x0 * bf2f(u0.y);
        acc.z += x0 * bf2f(u0.z); acc.w += x0 * bf2f(u0.w);
        acc.x += x1 * bf2f(u1.x); acc.y += x1 * bf2f(u1.y);
        acc.z += x1 * bf2f(u1.z); acc.w += x1 * bf2f(u1.w);
        acc.x += x2 * bf2f(u2.x); acc.y += x2 * bf2f(u2.y);
        acc.z += x2 * bf2f(u2.z); acc.w += x2 * bf2f(u2.w);
        acc.x += x3 * bf2f(u3.x); acc.y += x3 * bf2f(u3.y);
        acc.z += x3 * bf2f(u3.z); acc.w += x3 * bf2f(u3.w);
        sumex += x0 + x1 + x2 + x3;
    }
    for (; i < cnt; ++i) {
        int s = ep[i];
        float v = el[s * 4 + h] + er_nh;
        v = v > 0.f ? v : NEG_SLOPE * v;
        float ex = __expf(v);
        ushort4 u = *((const ushort4*)(fb + (size_t)s * 128));
        acc.x += ex * bf2f(u.x); acc.y += ex * bf2f(u.y);
        acc.z += ex * bf2f(u.z); acc.w += ex * bf2f(u.w);
        sumex += ex;
    }
    float inv = 1.f / ((sumex == 0.f) ? 1.f : sumex);
    float4 bb = *((const float4*)(b + h * 32 + d4 * 4));
    float4 o;
    o.x = acc.x * inv + bb.x;
    o.y = acc.y * inv + bb.y;
    o.z = acc.z * inv + bb.z;
    o.w = acc.w * inv + bb.w;
    // mean over heads: after xor-8/16 every lane holds the head-sum for its d4
    o.x += __shfl_xor(o.x, 8); o.x += __shfl_xor(o.x, 16);
    o.y += __shfl_xor(o.y, 8); o.y += __shfl_xor(o.y, 16);
    o.z += __shfl_xor(o.z, 8); o.z += __shfl_xor(o.z, 16);
    o.w += __shfl_xor(o.w, 8); o.w += __shfl_xor(o.w, 16);
    // hbuf row (in registers): hb chunk d4 = dims d4*4..d4*4+3, relu(mean)
    float4 hb;
    hb.x = fmaxf(o.x * 0.25f, 0.f);
    hb.y = fmaxf(o.y * 0.25f, 0.f);
    hb.z = fmaxf(o.z * 0.25f, 0.f);
    hb.w = fmaxf(o.w * 0.25f, 0.f);

    // ---- fused gemm2: feat2[n,c] = sum_k hb[k]*W2[k,c], c = lane&15 ----
    int c = lane & 15;
    const float* w2c = W2 + c;
    float fc = 0.f;
#pragma unroll
    for (int j = 0; j < 8; ++j) {
        float4 hbj;
        hbj.x = __shfl(hb.x, j, 32);
        hbj.y = __shfl(hb.y, j, 32);
        hbj.z = __shfl(hb.z, j, 32);
        hbj.w = __shfl(hb.w, j, 32);
        fc += hbj.x * w2c[(j * 4 + 0) * 16];
        fc += hbj.y * w2c[(j * 4 + 1) * 16];
        fc += hbj.z * w2c[(j * 4 + 2) * 16];
        fc += hbj.w * w2c[(j * 4 + 3) * 16];
    }
    float pl = fc * al2[c];
    float pr = fc * ar2[c];
    pl += __shfl_xor(pl, 1, 32); pl += __shfl_xor(pl, 2, 32);
    pl += __shfl_xor(pl, 4, 32); pl += __shfl_xor(pl, 8, 32);
    pr += __shfl_xor(pr, 1, 32); pr += __shfl_xor(pr, 2, 32);
    pr += __shfl_xor(pr, 4, 32); pr += __shfl_xor(pr, 8, 32);
    if (lane < 16) feat2[(size_t)node * 16 + c] = fc;
    if (lane == 0) {
        el2[node] = pl;
        er2[node] = pr;
    }
}

// ---------- layer-2 pull: 4 lanes/node (H=1, D=16), fp32 feat, 8x MLP -------
__global__ __launch_bounds__(256) void pull2_kernel(
    const int* __restrict__ rowptr, const int* __restrict__ deg,
    const int* __restrict__ esrc, const float* __restrict__ el,
    const float* __restrict__ er, const float* __restrict__ feat,
    const float* __restrict__ b, float* __restrict__ outp, int N) {
    int tid = blockIdx.x * 256 + threadIdx.x;
    int node = tid >> 2;
    int d4 = threadIdx.x & 3;
    if (node >= N) return;

    int start = rowptr[node];
    int cnt = deg[node];
    float er_n = er[node];
    const int* ep = esrc + start;
    const float* fb = feat + d4 * 4;

    float4 acc = make_float4(0.f, 0.f, 0.f, 0.f);
    float sumex = 0.f;
    int i = 0;
    for (; i + 8 <= cnt; i += 8) {
        int s[8];
#pragma unroll
        for (int j = 0; j < 8; ++j) s[j] = ep[i + j];
        float ee[8];
        float4 ff[8];
#pragma unroll
        for (int j = 0; j < 8; ++j) {
            ee[j] = el[s[j]];
            ff[j] = *((const float4*)(fb + (size_t)s[j] * 16));
        }
#pragma unroll
        for (int j = 0; j < 8; ++j) {
            float v = ee[j] + er_n;
            v = v > 0.f ? v : NEG_SLOPE * v;
            float ex = __expf(v);
            acc.x += ex * ff[j].x; acc.y += ex * ff[j].y;
            acc.z += ex * ff[j].z; acc.w += ex * ff[j].w;
            sumex += ex;
        }
    }
    for (; i + 4 <= cnt; i += 4) {
        int s[4];
#pragma unroll
        for (int j = 0; j < 4; ++j) s[j] = ep[i + j];
        float ee[4];
        float4 ff[4];
#pragma unroll
        for (int j = 0; j < 4; ++j) {
            ee[j] = el[s[j]];
            ff[j] = *((const float4*)(fb + (size_t)s[j] * 16));
        }
#pragma unroll
        for (int j = 0; j < 4; ++j) {
            float v = ee[j] + er_n;
            v = v > 0.f ? v : NEG_SLOPE * v;
            float ex = __expf(v);
            acc.x += ex * ff[j].x; acc.y += ex * ff[j].y;
            acc.z += ex * ff[j].z; acc.w += ex * ff[j].w;
            sumex += ex;
        }
    }
    for (; i < cnt; ++i) {
        int s = ep[i];
        float v = el[s] + er_n;
        v = v > 0.f ? v : NEG_SLOPE * v;
        float ex = __expf(v);
        float4 f = *((const float4*)(fb + (size_t)s * 16));
        acc.x += ex * f.x; acc.y += ex * f.y;
        acc.z += ex * f.z; acc.w += ex * f.w;
        sumex += ex;
    }
    float inv = 1.f / ((sumex == 0.f) ? 1.f : sumex);
    float4 bb = *((const float4*)(b + d4 * 4));
    float4 o;
    o.x = acc.x * inv + bb.x;
    o.y = acc.y * inv + bb.y;
    o.z = acc.z * inv + bb.z;
    o.w = acc.w * inv + bb.w;
    *((float4*)(outp + (size_t)node * 16 + d4 * 4)) = o;
}

extern "C" void kernel_launch(void* const* d_in, const int* in_sizes, int n_in,
                              void* d_out, int out_size, void* d_ws, size_t ws_size,
                              hipStream_t stream) {
    const float* x   = (const float*)d_in[0];
    const int*   src = (const int*)d_in[1];
    const int*   dst = (const int*)d_in[2];
    const float* W1  = (const float*)d_in[3];
    const float* al1 = (const float*)d_in[4];
    const float* ar1 = (const float*)d_in[5];
    const float* b1  = (const float*)d_in[6];
    const float* W2  = (const float*)d_in[7];
    const float* al2 = (const float*)d_in[8];
    const float* ar2 = (const float*)d_in[9];
    const float* b2  = (const float*)d_in[10];

    const int E = in_sizes[1];
    const int N = in_sizes[0] / 128;
    const int H1 = 4, D1 = 32, C1 = 128;
    const int D2 = 16;
    const int NB = (N + GSZ - 1) / GSZ;
    const int NCH = (E + CHUNK - 1) / CHUNK;
    const int NG = (N + 63) / 64;   // gemm1 blocks

    char* p = (char*)d_ws;
    auto alloc_f = [&](size_t n) { float* q = (float*)p; p += n * sizeof(float); return q; };
    auto alloc_i = [&](size_t n) { int* q = (int*)p; p += n * sizeof(int); return q; };

    __hip_bfloat16* feat1b = (__hip_bfloat16*)p; p += (size_t)N * C1 * sizeof(__hip_bfloat16);
    float* el1   = alloc_f((size_t)N * H1);
    float* er1   = alloc_f((size_t)N * H1);
    float* feat2 = alloc_f((size_t)N * D2);
    float* el2   = alloc_f(N);
    float* er2   = alloc_f(N);
    int* deg     = alloc_i(N);
    int* rowptr  = alloc_i(N);
    int* esrc    = alloc_i(E);
    int* gcursor = alloc_i(NB);
    unsigned* inter = (unsigned*)alloc_i((size_t)NB * CHUNK);

    const int TB = 256;
    auto blocks = [&](long long n) { return (int)((n + TB - 1) / TB); };

    // ---- CSR coarse pass ----
    hipMemsetAsync(gcursor, 0, (size_t)NB * sizeof(int), stream);
    coarse_scatter<<<NCH, TB, 0, stream>>>(src, dst, gcursor, inter, NB, E);

    // ---- gemm1 (+el/er) || fine scatter ----
    gemm1_fine_fused<<<NG + NB, TB, 0, stream>>>(
        x, W1, al1, ar1, feat1b, el1, er1, N, NG,
        inter, gcursor, deg, rowptr, esrc, NB);

    // ---- pull1 + fused gemm2/el2/er2 ----
    pull1_kernel<<<blocks((long long)N * 32), TB, 0, stream>>>(
        rowptr, deg, esrc, el1, er1, feat1b, b1,
        W2, al2, ar2, feat2, el2, er2, N);

    // ---- layer-2 pull ----
    pull2_kernel<<<blocks((long long)N * 4), TB, 0, stream>>>(
        rowptr, deg, esrc, el2, er2, feat2, b2, (float*)d_out, N);
}

// Round 11
// 284.569 us; speedup vs baseline: 1.4331x; 1.4331x over previous
//
#include <hip/hip_runtime.h>
#include <hip/hip_bf16.h>

#define NEG_SLOPE 0.2f
#define G_SHIFT 7
#define GSZ 128          // nodes per bucket
#define CHUNK 4096       // edges per coarse block; also per-bucket region capacity

// ---------- coarse scatter: bucket edges, u32-packed, coalesced writes ------
__global__ __launch_bounds__(256) void coarse_scatter(
    const int* __restrict__ src, const int* __restrict__ dst,
    int* __restrict__ gcursor, unsigned* __restrict__ inter, int NB, int E) {
    __shared__ int hist[800];
    __shared__ int lbase[800];
    __shared__ int gbase[800];
    __shared__ unsigned stage[CHUNK];
    __shared__ unsigned short bstage[CHUNK];

    const int tid = threadIdx.x;
    const int e0 = blockIdx.x * CHUNK;
    const int cnt = min(CHUNK, E - e0);

    for (int i = tid; i < NB; i += 256) hist[i] = 0;
    __syncthreads();

    unsigned pk[16];
    int bb[16];
#pragma unroll
    for (int r = 0; r < 16; ++r) {
        int idx = tid + r * 256;
        if (idx < cnt) {
            int s = src[e0 + idx];
            int d = dst[e0 + idx];
            pk[r] = ((unsigned)s << G_SHIFT) | (unsigned)(d & (GSZ - 1));
            bb[r] = d >> G_SHIFT;
            atomicAdd(&hist[bb[r]], 1);
        }
    }
    __syncthreads();
    if (tid < 64) {
        int carry = 0;
        for (int i = 0; i < NB; i += 64) {
            int v = (i + tid < NB) ? hist[i + tid] : 0;
            int xv = v;
            for (int o = 1; o < 64; o <<= 1) {
                int tt = __shfl_up(xv, o, 64);
                if (tid >= o) xv += tt;
            }
            if (i + tid < NB) lbase[i + tid] = carry + xv - v;
            carry += __shfl(xv, 63, 64);
        }
    }
    __syncthreads();
    for (int i = tid; i < NB; i += 256) {
        int hh = hist[i];
        gbase[i] = (hh > 0) ? (i * CHUNK + atomicAdd(&gcursor[i], hh)) : 0;
    }
    __syncthreads();
    for (int i = tid; i < NB; i += 256) hist[i] = 0;
    __syncthreads();
#pragma unroll
    for (int r = 0; r < 16; ++r) {
        int idx = tid + r * 256;
        if (idx < cnt) {
            int b = bb[r];
            int rk = atomicAdd(&hist[b], 1);
            int pos = lbase[b] + rk;
            stage[pos] = pk[r];
            bstage[pos] = (unsigned short)b;
        }
    }
    __syncthreads();
#pragma unroll
    for (int r = 0; r < 16; ++r) {
        int idx = tid + r * 256;
        if (idx < cnt) {
            int b = (int)bstage[idx];
            inter[gbase[b] + (idx - lbase[b])] = stage[idx];
        }
    }
}

// ---------- fine scatter: per-bucket CSR finalize (self-computed base) ------
__global__ __launch_bounds__(256) void fine_scatter(
    const unsigned* __restrict__ inter, const int* __restrict__ gcursor,
    int* __restrict__ deg, int* __restrict__ rowptr, int* __restrict__ esrc,
    int N, int NB) {
    __shared__ int h[GSZ];
    __shared__ int lb[GSZ];
    __shared__ int stage[CHUNK];
    __shared__ int redsum[256];
    const int b = blockIdx.x;
    const int tid = threadIdx.x;
    const int cnt = gcursor[b];
    const unsigned* ep = inter + (size_t)b * CHUNK;

    // bucket base = sum gcursor[0..b)
    {
        int s = 0;
        for (int i = tid; i < b; i += 256) s += gcursor[i];
        redsum[tid] = s;
        __syncthreads();
        for (int o = 128; o > 0; o >>= 1) {
            if (tid < o) redsum[tid] += redsum[tid + o];
            __syncthreads();
        }
    }
    const int base = redsum[0];

    if (tid < GSZ) h[tid] = 0;
    __syncthreads();

    int ss[16];
    unsigned char ln[16];
    int nr = 0;
    for (int idx = tid; idx < cnt; idx += 256) {
        unsigned ed = ep[idx];
        ss[nr] = (int)(ed >> G_SHIFT);
        int l = (int)(ed & (GSZ - 1));
        ln[nr++] = (unsigned char)l;
        atomicAdd(&h[l], 1);
    }
    __syncthreads();
    if (tid < 64) {
        int carry = 0;
        for (int i = 0; i < GSZ; i += 64) {
            int v = h[i + tid];
            int xv = v;
            for (int o = 1; o < 64; o <<= 1) {
                int tt = __shfl_up(xv, o, 64);
                if (tid >= o) xv += tt;
            }
            lb[i + tid] = carry + xv - v;
            carry += __shfl(xv, 63, 64);
        }
    }
    __syncthreads();
    if (tid < GSZ) {
        int node = b * GSZ + tid;
        if (node < N) {
            deg[node] = h[tid];
            rowptr[node] = base + lb[tid];
        }
        h[tid] = 0;
    }
    __syncthreads();
    for (int r = 0; r < nr; ++r) {
        int l = ln[r];
        int rk = atomicAdd(&h[l], 1);
        stage[lb[l] + rk] = ss[r];
    }
    __syncthreads();
    for (int idx = tid; idx < cnt; idx += 256) esrc[base + idx] = stage[idx];
}

// ---------- layer-1 GEMM (K=C=128) + fused el/er epilogue, bf16 feat out ----
__global__ __launch_bounds__(256) void gemm1_fused(
    const float* __restrict__ x, const float* __restrict__ W,
    const float* __restrict__ al, const float* __restrict__ ar,
    __hip_bfloat16* __restrict__ outb, float* __restrict__ el,
    float* __restrict__ er, int N) {
    const int K = 128, C = 128, BK = 32;
    __shared__ float xs[BK][68];
    __shared__ float ws[BK][C];

    const int t = threadIdx.x;
    const int trow = t >> 4;
    const int tcol = t & 15;
    const int m0 = blockIdx.x * 64;

    float acc[4][8];
#pragma unroll
    for (int i = 0; i < 4; ++i)
#pragma unroll
        for (int j = 0; j < 8; ++j) acc[i][j] = 0.f;

    for (int k0 = 0; k0 < K; k0 += BK) {
        {
            const float4* W4 = (const float4*)(W + k0 * C);
#pragma unroll
            for (int r = 0; r < 4; ++r) {
                int q = t + 256 * r;
                int k = q >> 5;
                int c4 = q & 31;
                float4 v = W4[k * 32 + c4];
                *((float4*)&ws[k][c4 * 4]) = v;
            }
        }
        {
#pragma unroll
            for (int r = 0; r < 2; ++r) {
                int q = t + 256 * r;
                int m = q >> 3;
                int k4 = q & 7;
                int gm = m0 + m;
                if (gm >= N) gm = N - 1;
                float4 v = *((const float4*)(x + (size_t)gm * K + k0 + k4 * 4));
                xs[k4 * 4 + 0][m] = v.x;
                xs[k4 * 4 + 1][m] = v.y;
                xs[k4 * 4 + 2][m] = v.z;
                xs[k4 * 4 + 3][m] = v.w;
            }
        }
        __syncthreads();

#pragma unroll
        for (int k = 0; k < BK; ++k) {
            float4 a = *((const float4*)&xs[k][trow * 4]);
            float4 b0 = *((const float4*)&ws[k][tcol * 8]);
            float4 b1 = *((const float4*)&ws[k][tcol * 8 + 4]);
            float av[4] = {a.x, a.y, a.z, a.w};
            float bv[8] = {b0.x, b0.y, b0.z, b0.w, b1.x, b1.y, b1.z, b1.w};
#pragma unroll
            for (int i = 0; i < 4; ++i)
#pragma unroll
                for (int j = 0; j < 8; ++j) acc[i][j] += av[i] * bv[j];
        }
        __syncthreads();
    }

    const int h = tcol >> 2;
    const int d0 = (tcol & 3) * 8;
    float alv[8], arv[8];
#pragma unroll
    for (int j = 0; j < 8; ++j) {
        alv[j] = al[h * 32 + d0 + j];
        arv[j] = ar[h * 32 + d0 + j];
    }
#pragma unroll
    for (int i = 0; i < 4; ++i) {
        int gm = m0 + trow * 4 + i;
        if (gm < N) {
            union { __hip_bfloat16 hh[8]; uint4 u; } pk;
#pragma unroll
            for (int j = 0; j < 8; ++j) pk.hh[j] = __float2bfloat16(acc[i][j]);
            *((uint4*)(outb + (size_t)gm * C + tcol * 8)) = pk.u;
        }
        float pl = 0.f, pr = 0.f;
#pragma unroll
        for (int j = 0; j < 8; ++j) {
            pl += acc[i][j] * alv[j];
            pr += acc[i][j] * arv[j];
        }
        pl += __shfl_xor(pl, 1); pl += __shfl_xor(pl, 2);
        pr += __shfl_xor(pr, 1); pr += __shfl_xor(pr, 2);
        if ((tcol & 3) == 0 && gm < N) {
            el[gm * 4 + h] = pl;
            er[gm * 4 + h] = pr;
        }
    }
}

__device__ __forceinline__ float bf2f(unsigned short v) {
    return __uint_as_float((unsigned)v << 16);
}

// ---------- layer-1 pull (32 lanes/node, 4x unroll) + fused gemm2/el2/er2 ---
__global__ __launch_bounds__(256) void pull1_kernel(
    const int* __restrict__ rowptr, const int* __restrict__ deg,
    const int* __restrict__ esrc, const float* __restrict__ el,
    const float* __restrict__ er, const __hip_bfloat16* __restrict__ featb,
    const float* __restrict__ b,
    const float* __restrict__ W2, const float* __restrict__ al2,
    const float* __restrict__ ar2, float* __restrict__ feat2,
    float* __restrict__ el2, float* __restrict__ er2, int N) {
    int tid = blockIdx.x * 256 + threadIdx.x;
    int node = tid >> 5;
    int lane = threadIdx.x & 31;
    int h = lane >> 3;
    int d4 = lane & 7;
    if (node >= N) return;

    int start = rowptr[node];
    int cnt = deg[node];
    float er_nh = er[node * 4 + h];
    const int* ep = esrc + start;
    const unsigned short* fb = (const unsigned short*)featb + h * 32 + d4 * 4;

    float4 acc = make_float4(0.f, 0.f, 0.f, 0.f);
    float sumex = 0.f;

    int i = 0;
    for (; i + 4 <= cnt; i += 4) {
        int s0 = ep[i], s1 = ep[i + 1], s2 = ep[i + 2], s3 = ep[i + 3];
        float e0 = el[s0 * 4 + h], e1 = el[s1 * 4 + h];
        float e2 = el[s2 * 4 + h], e3 = el[s3 * 4 + h];
        ushort4 u0 = *((const ushort4*)(fb + (size_t)s0 * 128));
        ushort4 u1 = *((const ushort4*)(fb + (size_t)s1 * 128));
        ushort4 u2 = *((const ushort4*)(fb + (size_t)s2 * 128));
        ushort4 u3 = *((const ushort4*)(fb + (size_t)s3 * 128));
        float v0 = e0 + er_nh; v0 = v0 > 0.f ? v0 : NEG_SLOPE * v0;
        float v1 = e1 + er_nh; v1 = v1 > 0.f ? v1 : NEG_SLOPE * v1;
        float v2 = e2 + er_nh; v2 = v2 > 0.f ? v2 : NEG_SLOPE * v2;
        float v3 = e3 + er_nh; v3 = v3 > 0.f ? v3 : NEG_SLOPE * v3;
        float x0 = __expf(v0), x1 = __expf(v1), x2 = __expf(v2), x3 = __expf(v3);
        acc.x += x0 * bf2f(u0.x); acc.y += x0 * bf2f(u0.y);
        acc.z += x0 * bf2f(u0.z); acc.w += x0 * bf2f(u0.w);
        acc.x += x1 * bf2f(u1.x); acc.y += x1 * bf2f(u1.y);
        acc.z += x1 * bf2f(u1.z); acc.w += x1 * bf2f(u1.w);
        acc.x += x2 * bf2f(u2.x); acc.y += x2 * bf2f(u2.y);
        acc.z += x2 * bf2f(u2.z); acc.w += x2 * bf2f(u2.w);
        acc.x += x3 * bf2f(u3.x); acc.y += x3 * bf2f(u3.y);
        acc.z += x3 * bf2f(u3.z); acc.w += x3 * bf2f(u3.w);
        sumex += x0 + x1 + x2 + x3;
    }
    for (; i < cnt; ++i) {
        int s = ep[i];
        float v = el[s * 4 + h] + er_nh;
        v = v > 0.f ? v : NEG_SLOPE * v;
        float ex = __expf(v);
        ushort4 u = *((const ushort4*)(fb + (size_t)s * 128));
        acc.x += ex * bf2f(u.x); acc.y += ex * bf2f(u.y);
        acc.z += ex * bf2f(u.z); acc.w += ex * bf2f(u.w);
        sumex += ex;
    }
    float inv = 1.f / ((sumex == 0.f) ? 1.f : sumex);
    float4 bb = *((const float4*)(b + h * 32 + d4 * 4));
    float4 o;
    o.x = acc.x * inv + bb.x;
    o.y = acc.y * inv + bb.y;
    o.z = acc.z * inv + bb.z;
    o.w = acc.w * inv + bb.w;
    // mean over heads: after xor-8/16 every lane holds the head-sum for its d4
    o.x += __shfl_xor(o.x, 8); o.x += __shfl_xor(o.x, 16);
    o.y += __shfl_xor(o.y, 8); o.y += __shfl_xor(o.y, 16);
    o.z += __shfl_xor(o.z, 8); o.z += __shfl_xor(o.z, 16);
    o.w += __shfl_xor(o.w, 8); o.w += __shfl_xor(o.w, 16);
    float4 hb;
    hb.x = fmaxf(o.x * 0.25f, 0.f);
    hb.y = fmaxf(o.y * 0.25f, 0.f);
    hb.z = fmaxf(o.z * 0.25f, 0.f);
    hb.w = fmaxf(o.w * 0.25f, 0.f);

    // ---- fused gemm2: feat2[n,c] = sum_k hb[k]*W2[k,c], c = lane&15 ----
    int c = lane & 15;
    const float* w2c = W2 + c;
    float fc = 0.f;
#pragma unroll
    for (int j = 0; j < 8; ++j) {
        float4 hbj;
        hbj.x = __shfl(hb.x, j, 32);
        hbj.y = __shfl(hb.y, j, 32);
        hbj.z = __shfl(hb.z, j, 32);
        hbj.w = __shfl(hb.w, j, 32);
        fc += hbj.x * w2c[(j * 4 + 0) * 16];
        fc += hbj.y * w2c[(j * 4 + 1) * 16];
        fc += hbj.z * w2c[(j * 4 + 2) * 16];
        fc += hbj.w * w2c[(j * 4 + 3) * 16];
    }
    float pl = fc * al2[c];
    float pr = fc * ar2[c];
    pl += __shfl_xor(pl, 1, 32); pl += __shfl_xor(pl, 2, 32);
    pl += __shfl_xor(pl, 4, 32); pl += __shfl_xor(pl, 8, 32);
    pr += __shfl_xor(pr, 1, 32); pr += __shfl_xor(pr, 2, 32);
    pr += __shfl_xor(pr, 4, 32); pr += __shfl_xor(pr, 8, 32);
    if (lane < 16) feat2[(size_t)node * 16 + c] = fc;
    if (lane == 0) {
        el2[node] = pl;
        er2[node] = pr;
    }
}

// ---------- layer-2 pull: 4 lanes/node (H=1, D=16), fp32 feat, 8x MLP -------
__global__ __launch_bounds__(256) void pull2_kernel(
    const int* __restrict__ rowptr, const int* __restrict__ deg,
    const int* __restrict__ esrc, const float* __restrict__ el,
    const float* __restrict__ er, const float* __restrict__ feat,
    const float* __restrict__ b, float* __restrict__ outp, int N) {
    int tid = blockIdx.x * 256 + threadIdx.x;
    int node = tid >> 2;
    int d4 = threadIdx.x & 3;
    if (node >= N) return;

    int start = rowptr[node];
    int cnt = deg[node];
    float er_n = er[node];
    const int* ep = esrc + start;
    const float* fb = feat + d4 * 4;

    float4 acc = make_float4(0.f, 0.f, 0.f, 0.f);
    float sumex = 0.f;
    int i = 0;
    for (; i + 8 <= cnt; i += 8) {
        int s[8];
#pragma unroll
        for (int j = 0; j < 8; ++j) s[j] = ep[i + j];
        float ee[8];
        float4 ff[8];
#pragma unroll
        for (int j = 0; j < 8; ++j) {
            ee[j] = el[s[j]];
            ff[j] = *((const float4*)(fb + (size_t)s[j] * 16));
        }
#pragma unroll
        for (int j = 0; j < 8; ++j) {
            float v = ee[j] + er_n;
            v = v > 0.f ? v : NEG_SLOPE * v;
            float ex = __expf(v);
            acc.x += ex * ff[j].x; acc.y += ex * ff[j].y;
            acc.z += ex * ff[j].z; acc.w += ex * ff[j].w;
            sumex += ex;
        }
    }
    for (; i + 4 <= cnt; i += 4) {
        int s[4];
#pragma unroll
        for (int j = 0; j < 4; ++j) s[j] = ep[i + j];
        float ee[4];
        float4 ff[4];
#pragma unroll
        for (int j = 0; j < 4; ++j) {
            ee[j] = el[s[j]];
            ff[j] = *((const float4*)(fb + (size_t)s[j] * 16));
        }
#pragma unroll
        for (int j = 0; j < 4; ++j) {
            float v = ee[j] + er_n;
            v = v > 0.f ? v : NEG_SLOPE * v;
            float ex = __expf(v);
            acc.x += ex * ff[j].x; acc.y += ex * ff[j].y;
            acc.z += ex * ff[j].z; acc.w += ex * ff[j].w;
            sumex += ex;
        }
    }
    for (; i < cnt; ++i) {
        int s = ep[i];
        float v = el[s] + er_n;
        v = v > 0.f ? v : NEG_SLOPE * v;
        float ex = __expf(v);
        float4 f = *((const float4*)(fb + (size_t)s * 16));
        acc.x += ex * f.x; acc.y += ex * f.y;
        acc.z += ex * f.z; acc.w += ex * f.w;
        sumex += ex;
    }
    float inv = 1.f / ((sumex == 0.f) ? 1.f : sumex);
    float4 bb = *((const float4*)(b + d4 * 4));
    float4 o;
    o.x = acc.x * inv + bb.x;
    o.y = acc.y * inv + bb.y;
    o.z = acc.z * inv + bb.z;
    o.w = acc.w * inv + bb.w;
    *((float4*)(outp + (size_t)node * 16 + d4 * 4)) = o;
}

extern "C" void kernel_launch(void* const* d_in, const int* in_sizes, int n_in,
                              void* d_out, int out_size, void* d_ws, size_t ws_size,
                              hipStream_t stream) {
    const float* x   = (const float*)d_in[0];
    const int*   src = (const int*)d_in[1];
    const int*   dst = (const int*)d_in[2];
    const float* W1  = (const float*)d_in[3];
    const float* al1 = (const float*)d_in[4];
    const float* ar1 = (const float*)d_in[5];
    const float* b1  = (const float*)d_in[6];
    const float* W2  = (const float*)d_in[7];
    const float* al2 = (const float*)d_in[8];
    const float* ar2 = (const float*)d_in[9];
    const float* b2  = (const float*)d_in[10];

    const int E = in_sizes[1];
    const int N = in_sizes[0] / 128;
    const int H1 = 4, C1 = 128;
    const int D2 = 16;
    const int NB = (N + GSZ - 1) / GSZ;
    const int NCH = (E + CHUNK - 1) / CHUNK;

    char* p = (char*)d_ws;
    auto alloc_f = [&](size_t n) { float* q = (float*)p; p += n * sizeof(float); return q; };
    auto alloc_i = [&](size_t n) { int* q = (int*)p; p += n * sizeof(int); return q; };

    __hip_bfloat16* feat1b = (__hip_bfloat16*)p; p += (size_t)N * C1 * sizeof(__hip_bfloat16);
    float* el1   = alloc_f((size_t)N * H1);
    float* er1   = alloc_f((size_t)N * H1);
    float* feat2 = alloc_f((size_t)N * D2);
    float* el2   = alloc_f(N);
    float* er2   = alloc_f(N);
    int* deg     = alloc_i(N);
    int* rowptr  = alloc_i(N);
    int* esrc    = alloc_i(E);
    int* gcursor = alloc_i(NB);
    unsigned* inter = (unsigned*)alloc_i((size_t)NB * CHUNK);

    const int TB = 256;
    auto blocks = [&](long long n) { return (int)((n + TB - 1) / TB); };

    // ---- CSR build ----
    hipMemsetAsync(gcursor, 0, (size_t)NB * sizeof(int), stream);
    coarse_scatter<<<NCH, TB, 0, stream>>>(src, dst, gcursor, inter, NB, E);
    fine_scatter<<<NB, TB, 0, stream>>>(inter, gcursor, deg, rowptr, esrc, N, NB);

    // ---- layer 1 ----
    gemm1_fused<<<(N + 63) / 64, TB, 0, stream>>>(x, W1, al1, ar1, feat1b, el1, er1, N);
    pull1_kernel<<<blocks((long long)N * 32), TB, 0, stream>>>(
        rowptr, deg, esrc, el1, er1, feat1b, b1,
        W2, al2, ar2, feat2, el2, er2, N);

    // ---- layer 2 ----
    pull2_kernel<<<blocks((long long)N * 4), TB, 0, stream>>>(
        rowptr, deg, esrc, el2, er2, feat2, b2, (float*)d_out, N);
}